// Round 4
// baseline (252.535 us; speedup 1.0000x reference)
//
#include <hip/hip_runtime.h>
#include <math.h>

// out[b,c,n] = softmax_n(max_c x[b,c,n]) * x[b,c,n]   (x: [256,64,2048] fp32)
// R1-R3: single fused kernel stuck at 90us / 2.97 TB/s regardless of
// occupancy (19->38%) and loop-phase rotation. Hypothesis: the two phases
// are serialized per-direction streams (~3.15 TB/s each way); the m13
// 6.3 TB/s copy figure is read+write aggregate. R4: split into 3 kernels
// to (a) give every phase a flat, many-blocks/CU copy-shaped pattern and
// (b) get per-phase BW from rocprof per-dispatch counters.

#define B_DIM 256
#define C_DIM 64
#define N_DIM 2048
#define COLS4 (N_DIM / 4)          // 512 float4 per row
#define ROWS_PER_PB 16             // K1: rows per partial block
#define PB_PER_B (C_DIM / ROWS_PER_PB)   // 4 partials per batch
#define NUM_PB (B_DIM * PB_PER_B)        // 1024 partial blocks

static __device__ __forceinline__ float4 max4(float4 a, float4 b) {
    float4 r;
    r.x = fmaxf(a.x, b.x); r.y = fmaxf(a.y, b.y);
    r.z = fmaxf(a.z, b.z); r.w = fmaxf(a.w, b.w);
    return r;
}

// ---- K1: partial column-max over 16 contiguous rows (128 KiB/block) ----
__global__ __launch_bounds__(256)
void k1_partial_max(const float* __restrict__ x, float4* __restrict__ part) {
    const int pb = blockIdx.x;                 // 0..1023
    const int t  = threadIdx.x;                // 0..255
    const float4* __restrict__ xb =
        (const float4*)x + (size_t)pb * ROWS_PER_PB * COLS4;
    float4 m0, m1;
    m0.x = m0.y = m0.z = m0.w = -INFINITY;
    m1 = m0;
    #pragma unroll
    for (int r = 0; r < ROWS_PER_PB; ++r) {
        float4 a = xb[r * COLS4 + t];
        float4 b = xb[r * COLS4 + t + 256];
        m0 = max4(m0, a);
        m1 = max4(m1, b);
    }
    part[(size_t)pb * COLS4 + t]       = m0;
    part[(size_t)pb * COLS4 + t + 256] = m1;
}

// ---- K2: combine partials + softmax -> gate[b][n] ----
__global__ __launch_bounds__(512)
void k2_softmax(const float4* __restrict__ part, float4* __restrict__ gate) {
    const int b    = blockIdx.x;               // 0..255
    const int t    = threadIdx.x;              // 0..511 (one float4 col each)
    const int lane = t & 63;
    const int wid  = t >> 6;                   // 0..7

    __shared__ float sred[16];

    const float4* __restrict__ pb = part + (size_t)b * PB_PER_B * COLS4;
    float4 m = pb[t];
    #pragma unroll
    for (int p = 1; p < PB_PER_B; ++p) m = max4(m, pb[p * COLS4 + t]);

    float tm = fmaxf(fmaxf(m.x, m.y), fmaxf(m.z, m.w));
    #pragma unroll
    for (int off = 32; off > 0; off >>= 1)
        tm = fmaxf(tm, __shfl_down(tm, off, 64));
    if (lane == 0) sred[wid] = tm;
    __syncthreads();
    float M = sred[0];
    #pragma unroll
    for (int i = 1; i < 8; ++i) M = fmaxf(M, sred[i]);

    float4 e;
    e.x = __expf(m.x - M);
    e.y = __expf(m.y - M);
    e.z = __expf(m.z - M);
    e.w = __expf(m.w - M);
    float ts = (e.x + e.y) + (e.z + e.w);
    #pragma unroll
    for (int off = 32; off > 0; off >>= 1)
        ts += __shfl_down(ts, off, 64);
    if (lane == 0) sred[8 + wid] = ts;
    __syncthreads();
    float S = 0.0f;
    #pragma unroll
    for (int i = 8; i < 16; ++i) S += sred[i];

    const float inv = 1.0f / S;
    float4 g;
    g.x = e.x * inv; g.y = e.y * inv; g.z = e.z * inv; g.w = e.w * inv;
    gate[(size_t)b * COLS4 + t] = g;
}

// ---- K3: flat elementwise multiply, copy-shaped ----
// total float4 = 256*64*512 = 8,388,608; 8192 blocks x 256 thr x 4 f4
__global__ __launch_bounds__(256)
void k3_mul(const float4* __restrict__ x, const float4* __restrict__ gate,
            float4* __restrict__ out) {
    const size_t i0 = (size_t)blockIdx.x * 1024 + threadIdx.x;
    #pragma unroll
    for (int k = 0; k < 4; ++k) {
        const size_t i4 = i0 + (size_t)k * 256;
        float4 v = x[i4];
        const int col = (int)(i4 & (COLS4 - 1));
        const int b   = (int)(i4 >> 15);       // 64*512 f4 per batch
        float4 g = gate[(size_t)b * COLS4 + col];
        v.x *= g.x; v.y *= g.y; v.z *= g.z; v.w *= g.w;
        out[i4] = v;
    }
}

extern "C" void kernel_launch(void* const* d_in, const int* in_sizes, int n_in,
                              void* d_out, int out_size, void* d_ws, size_t ws_size,
                              hipStream_t stream) {
    const float* x = (const float*)d_in[0];
    float* out = (float*)d_out;

    // ws layout: partials (1024*512 float4 = 8 MiB) then gate (2 MiB)
    float4* part = (float4*)d_ws;
    float4* gate = part + (size_t)NUM_PB * COLS4;

    k1_partial_max<<<NUM_PB, 256, 0, stream>>>(x, part);
    k2_softmax<<<B_DIM, 512, 0, stream>>>(part, gate);
    k3_mul<<<8192, 256, 0, stream>>>((const float4*)x, gate, (float4*)out);
}